// Round 4
// baseline (106.833 us; speedup 1.0000x reference)
//
#include <hip/hip_runtime.h>
#include <hip/hip_bf16.h>

// Co-attention layer, factorized + packed + wave-pair split.
//   G_pre[l,r] = x_l*x_r*C1[l,r] + x_l*C2[l,r] + x_r*C3[l,r] + C4[l,r]
//   (C1..C4 weight-only, precomputed into d_ws, pre-scaled by 2*log2e)
//   tanh(g) = 1 - 2*rcp(exp2(g')+1); softmax shift-invariance -> only
//   S = sum rcp(...) accumulated, softmax arg = -2*log2e*S.
// Block = 128 threads = 2 waves covering 64 elements; wave parity p owns
// l in [8p, 8p+8). p is wave-uniform (readfirstlane) so C/dW stay on the
// scalar (s_load) path. Combine via LDS (3 barriers). Target 8 waves/SIMD.

typedef __attribute__((ext_vector_type(2))) float v2f;

#if __has_builtin(__builtin_amdgcn_exp2f)
#define EXP2F(v) __builtin_amdgcn_exp2f(v)
#else
#define EXP2F(v) exp2f(v)
#endif

#if __has_builtin(__builtin_amdgcn_rcpf)
#define RCPF(v) __builtin_amdgcn_rcpf(v)
#else
#define RCPF(v) (1.0f / (v))
#endif

#define LOG2E 1.4426950408889634f

__device__ __forceinline__ v2f fma2(v2f a, v2f b, v2f c) {
    return __builtin_elementwise_fma(a, b, c);
}

// ---------------- setup: C1..C4 (4 x 16 x 16 floats) into d_ws ----------------
__global__ __launch_bounds__(256) void coattn_setup(
    const float* __restrict__ emb_W,
    const float* __restrict__ emb_b,
    const float* __restrict__ M,
    float* __restrict__ C)
{
    const int t = threadIdx.x;          // one thread per (l, r) pair
    const int l = t >> 4;
    const int r = t & 15;

    float MW[8], Mb[8];
    #pragma unroll
    for (int e = 0; e < 8; ++e) {
        float s1 = 0.0f, s2 = 0.0f;
        #pragma unroll
        for (int f = 0; f < 8; ++f) {
            float m = M[e * 8 + f];
            s1 = fmaf(m, emb_W[(16 + r) * 8 + f], s1);
            s2 = fmaf(m, emb_b[(16 + r) * 8 + f], s2);
        }
        MW[e] = s1; Mb[e] = s2;
    }
    float c1 = 0.0f, c2 = 0.0f, c3 = 0.0f, c4 = 0.0f;
    #pragma unroll
    for (int e = 0; e < 8; ++e) {
        float w = emb_W[l * 8 + e];
        float b = emb_b[l * 8 + e];
        c1 = fmaf(w, MW[e], c1);
        c2 = fmaf(w, Mb[e], c2);
        c3 = fmaf(b, MW[e], c3);
        c4 = fmaf(b, Mb[e], c4);
    }
    const float s = 2.0f * LOG2E;
    C[0 * 256 + l * 16 + r] = c1 * s;
    C[1 * 256 + l * 16 + r] = c2 * s;
    C[2 * 256 + l * 16 + r] = c3 * s;
    C[3 * 256 + l * 16 + r] = c4 * s;
}

// Dense tail, templated on wave parity P so every register-array index is
// compile-time constant (runtime-indexed ext_vector arrays go to scratch).
template<int P>
__device__ __forceinline__ void dense_tail(
    const v2f (&xl2)[4], const v2f (&xr2)[8], const v2f (&elr)[8],
    float invlr, float invrl, const float (&er)[8],
    const v2f* __restrict__ dW2, const v2f* __restrict__ db2v,
    v2f* __restrict__ slot,          // my LDS slot (>= 4 v2f)
    v2f& r0, v2f& r1, v2f& r2, v2f& r3)
{
    v2f xa[8];
    #pragma unroll
    for (int i = 0; i < 4; ++i)
        xa[i] = xl2[i] * (elr[4 * P + i] * invlr);          // x[8P+..]*a_lr
    #pragma unroll
    for (int i = 0; i < 4; ++i) {
        v2f a; a.x = er[2 * i] * invrl; a.y = er[2 * i + 1] * invrl;
        xa[4 + i] = xr2[4 * P + i] * a;                     // x[16+8P+..]*a_rl
    }

    v2f o2[8];
    #pragma unroll
    for (int m = 0; m < 8; ++m) o2[m] = (v2f){0.0f, 0.0f};
    #pragma unroll
    for (int m = 0; m < 4; ++m) o2[4 * P + m] = db2v[4 * P + m];

    // lr rows: j = 8P + i2
    #pragma unroll
    for (int i2 = 0; i2 < 8; ++i2) {
        const float xj = xa[i2 >> 1][i2 & 1];
        const v2f xj2 = (v2f){xj, xj};
        const v2f* row = dW2 + (8 * P + i2) * 8;
        #pragma unroll
        for (int m = 0; m < 8; ++m) o2[m] = fma2(xj2, row[m], o2[m]);
    }
    // rl rows: j = 16 + 8P + i2
    #pragma unroll
    for (int i2 = 0; i2 < 8; ++i2) {
        const float xj = xa[4 + (i2 >> 1)][i2 & 1];
        const v2f xj2 = (v2f){xj, xj};
        const v2f* row = dW2 + (16 + 8 * P + i2) * 8;
        #pragma unroll
        for (int m = 0; m < 8; ++m) o2[m] = fma2(xj2, row[m], o2[m]);
    }

    // ship the OTHER parity's output half; keep my half in regs
    #pragma unroll
    for (int m = 0; m < 4; ++m) slot[m] = o2[4 * (1 - P) + m];
    r0 = o2[4 * P + 0]; r1 = o2[4 * P + 1];
    r2 = o2[4 * P + 2]; r3 = o2[4 * P + 3];
}

__global__ __launch_bounds__(128, 8) void coattn_kernel(
    const float* __restrict__ x,
    const float* __restrict__ C,
    const float* __restrict__ dW,
    const float* __restrict__ db,
    float* __restrict__ out)
{
    #pragma clang fp contract(off)

    __shared__ float ldsS[128 * 16];    // 8 KB: Scol exchange, then o exchange
    __shared__ float ldsP[128];         // rl-denominator partials

    const int tid  = threadIdx.x;
    const int lane = tid & 63;
    const int p    = __builtin_amdgcn_readfirstlane(tid >> 6);  // wave parity
    const long e   = (long)blockIdx.x * 64 + lane;

    // ---- load x: xl = x[8p..8p+8), xr = x[16..32) ----
    v2f xl2[4], xr2[8];
    {
        const float4* xp = reinterpret_cast<const float4*>(x + e * 32);
        float4 a0 = xp[2 * p], a1 = xp[2 * p + 1];
        xl2[0] = (v2f){a0.x, a0.y}; xl2[1] = (v2f){a0.z, a0.w};
        xl2[2] = (v2f){a1.x, a1.y}; xl2[3] = (v2f){a1.z, a1.w};
        #pragma unroll
        for (int k = 0; k < 4; ++k) {
            float4 v = xp[4 + k];
            xr2[2*k] = (v2f){v.x, v.y}; xr2[2*k+1] = (v2f){v.z, v.w};
        }
    }

    const v2f* C1 = reinterpret_cast<const v2f*>(C) + p * 64;   // rows 8p..
    const v2f* C2 = reinterpret_cast<const v2f*>(C) + 128 + p * 64;
    const v2f* C3 = reinterpret_cast<const v2f*>(C) + 256 + p * 64;
    const v2f* C4 = reinterpret_cast<const v2f*>(C) + 384 + p * 64;

    // ---- G over own 8 l's x all 16 r's ----
    v2f Scol[8];
    #pragma unroll
    for (int k = 0; k < 8; ++k) Scol[k] = (v2f){0.0f, 0.0f};
    float Srow[8];

    #pragma unroll
    for (int l = 0; l < 8; ++l) {
        const float xl_ = xl2[l >> 1][l & 1];
        const v2f xlv = (v2f){xl_, xl_};
        v2f rs = (v2f){0.0f, 0.0f};
        #pragma unroll
        for (int k = 0; k < 8; ++k) {
            v2f u = xlv * C1[l * 8 + k]; u = u + C3[l * 8 + k];
            v2f w = xlv * C2[l * 8 + k]; w = w + C4[l * 8 + k];
            v2f g = fma2(xr2[k], u, w);
            v2f E; E.x = EXP2F(g.x); E.y = EXP2F(g.y);
            v2f D = E + 1.0f;
            v2f rc; rc.x = RCPF(D.x); rc.y = RCPF(D.y);
            Scol[k] = Scol[k] + rc;
            rs = rs + rc;
        }
        Srow[l] = rs.x + rs.y;
    }

    const float NSCL = -2.0f * LOG2E;
    float er[8], pd = 0.0f;
    #pragma unroll
    for (int l = 0; l < 8; ++l) { er[l] = EXP2F(Srow[l] * NSCL); pd += er[l]; }

    // ---- exchange 1: Scol partials + rl-denominator partial ----
    {
        v2f* myS = reinterpret_cast<v2f*>(ldsS + tid * 16);
        #pragma unroll
        for (int k = 0; k < 8; ++k) myS[k] = Scol[k];
        ldsP[tid] = pd;
    }
    __syncthreads();
    float denr;
    {
        const int q = tid ^ 64;
        const v2f* pS = reinterpret_cast<const v2f*>(ldsS + q * 16);
        #pragma unroll
        for (int k = 0; k < 8; ++k) Scol[k] = Scol[k] + pS[k];
        denr = pd + ldsP[q];
    }

    // ---- softmaxes (lr fully redundant; rl own-half) ----
    v2f elr[8];
    float s = 0.0f;
    #pragma unroll
    for (int k = 0; k < 8; ++k) {
        v2f arg = Scol[k] * NSCL;
        v2f ee; ee.x = EXP2F(arg.x); ee.y = EXP2F(arg.y);
        elr[k] = ee;
        s += ee.x + ee.y;
    }
    const float invlr = RCPF(s);
    const float invrl = RCPF(denr);

    __syncthreads();    // phase-1 reads done before slot rewrite

    // ---- dense (j split by parity), ship other half via LDS ----
    const v2f* dW2  = reinterpret_cast<const v2f*>(dW);
    const v2f* db2v = reinterpret_cast<const v2f*>(db);
    v2f* slot = reinterpret_cast<v2f*>(ldsS + tid * 16);
    v2f r0, r1, r2, r3;
    if (p == 0)
        dense_tail<0>(xl2, xr2, elr, invlr, invrl, er, dW2, db2v, slot, r0, r1, r2, r3);
    else
        dense_tail<1>(xl2, xr2, elr, invlr, invrl, er, dW2, db2v, slot, r0, r1, r2, r3);

    __syncthreads();

    {
        const v2f* ps = reinterpret_cast<const v2f*>(ldsS + (tid ^ 64) * 16);
        v2f z = (v2f){0.0f, 0.0f};
        v2f f0 = __builtin_elementwise_max(r0 + ps[0], z);
        v2f f1 = __builtin_elementwise_max(r1 + ps[1], z);
        v2f f2 = __builtin_elementwise_max(r2 + ps[2], z);
        v2f f3 = __builtin_elementwise_max(r3 + ps[3], z);
        float4* op = reinterpret_cast<float4*>(out + e * 16 + p * 8);
        float4 v0; v0.x = f0.x; v0.y = f0.y; v0.z = f1.x; v0.w = f1.y;
        float4 v1; v1.x = f2.x; v1.y = f2.y; v1.z = f3.x; v1.w = f3.y;
        op[0] = v0;
        op[1] = v1;
    }
}

extern "C" void kernel_launch(void* const* d_in, const int* in_sizes, int n_in,
                              void* d_out, int out_size, void* d_ws, size_t ws_size,
                              hipStream_t stream) {
    const float* x     = (const float*)d_in[0];
    const float* emb_W = (const float*)d_in[1];
    const float* emb_b = (const float*)d_in[2];
    const float* M     = (const float*)d_in[3];
    const float* dW    = (const float*)d_in[4];
    const float* db    = (const float*)d_in[5];
    float* out = (float*)d_out;
    float* C   = (float*)d_ws;          // 4 * 256 floats = 4 KB

    hipLaunchKernelGGL(coattn_setup, dim3(1), dim3(256), 0, stream,
                       emb_W, emb_b, M, C);

    const int B = in_sizes[0] / 32;     // 262144
    dim3 block(128);
    dim3 grid(B / 64);                  // 2 waves per 64 elements
    hipLaunchKernelGGL(coattn_kernel, grid, block, 0, stream,
                       x, C, dW, db, out);
}

// Round 5
// 106.667 us; speedup vs baseline: 1.0016x; 1.0016x over previous
//
#include <hip/hip_runtime.h>
#include <hip/hip_bf16.h>

// Co-attention layer, factorized + packed + 4-wave split.
//   G_pre[l,r] = x_l*x_r*C1[l,r] + x_l*C2[l,r] + x_r*C3[l,r] + C4[l,r]
//   (C1..C4 weight-only, precomputed into d_ws, pre-scaled by 2*log2e)
//   tanh(g) = 1 - 2*rcp(exp2(g')+1); softmax shift-invariance -> only
//   S = sum rcp(...) accumulated, softmax arg = -2*log2e*S.
// Block = 256 threads = 4 waves over 64 elements. Wave w owns l in
// [4w,4w+4) and dense rows {4w..4w+4} u {16+4w..16+4w+4}. w is wave-
// uniform (readfirstlane) so C/dW stay on the scalar (s_load) path.
// Runtime-w register-array indexing avoided (rule #20): quarters are
// re-read via LDS; x[16+4w..] gets a dedicated load. 3 barriers.

typedef __attribute__((ext_vector_type(2))) float v2f;

#if __has_builtin(__builtin_amdgcn_exp2f)
#define EXP2F(v) __builtin_amdgcn_exp2f(v)
#else
#define EXP2F(v) exp2f(v)
#endif

#if __has_builtin(__builtin_amdgcn_rcpf)
#define RCPF(v) __builtin_amdgcn_rcpf(v)
#else
#define RCPF(v) (1.0f / (v))
#endif

#define LOG2E 1.4426950408889634f

__device__ __forceinline__ v2f fma2(v2f a, v2f b, v2f c) {
    return __builtin_elementwise_fma(a, b, c);
}

// ---------------- setup: C1..C4 (4 x 16 x 16 floats) into d_ws ----------------
__global__ __launch_bounds__(256) void coattn_setup(
    const float* __restrict__ emb_W,
    const float* __restrict__ emb_b,
    const float* __restrict__ M,
    float* __restrict__ C)
{
    const int t = threadIdx.x;          // one thread per (l, r) pair
    const int l = t >> 4;
    const int r = t & 15;

    float MW[8], Mb[8];
    #pragma unroll
    for (int e = 0; e < 8; ++e) {
        float s1 = 0.0f, s2 = 0.0f;
        #pragma unroll
        for (int f = 0; f < 8; ++f) {
            float m = M[e * 8 + f];
            s1 = fmaf(m, emb_W[(16 + r) * 8 + f], s1);
            s2 = fmaf(m, emb_b[(16 + r) * 8 + f], s2);
        }
        MW[e] = s1; Mb[e] = s2;
    }
    float c1 = 0.0f, c2 = 0.0f, c3 = 0.0f, c4 = 0.0f;
    #pragma unroll
    for (int e = 0; e < 8; ++e) {
        float w = emb_W[l * 8 + e];
        float b = emb_b[l * 8 + e];
        c1 = fmaf(w, MW[e], c1);
        c2 = fmaf(w, Mb[e], c2);
        c3 = fmaf(b, MW[e], c3);
        c4 = fmaf(b, Mb[e], c4);
    }
    const float s = 2.0f * LOG2E;
    C[0 * 256 + l * 16 + r] = c1 * s;
    C[1 * 256 + l * 16 + r] = c2 * s;
    C[2 * 256 + l * 16 + r] = c3 * s;
    C[3 * 256 + l * 16 + r] = c4 * s;
}

__global__ __launch_bounds__(256) void coattn_kernel(
    const float* __restrict__ x,
    const float* __restrict__ C,
    const float* __restrict__ dW,
    const float* __restrict__ db,
    float* __restrict__ out)
{
    #pragma clang fp contract(off)

    // slot stride 18 floats (72 B): 8-byte aligned rows, banks spread 16-ways
    __shared__ float ldsS[256 * 18];    // 18 KB: Scol exchange, then o exchange
    __shared__ float ldsP[256];         // rl-denominator partials

    const int tid  = threadIdx.x;
    const int lane = tid & 63;
    const int w    = __builtin_amdgcn_readfirstlane(tid >> 6);  // wave idx 0..3
    const long e   = (long)blockIdx.x * 64 + lane;
    const float* xe = x + e * 32;

    // ---- loads: xl = x[4w..4w+4), xr = x[16..32), xrl = x[16+4w..16+4w+4) ----
    v2f xl2[2], xr2[8], xrl2[2];
    {
        float4 t0 = *reinterpret_cast<const float4*>(xe + 4 * w);
        xl2[0] = (v2f){t0.x, t0.y}; xl2[1] = (v2f){t0.z, t0.w};
        #pragma unroll
        for (int k = 0; k < 4; ++k) {
            float4 v = *reinterpret_cast<const float4*>(xe + 16 + 4 * k);
            xr2[2*k] = (v2f){v.x, v.y}; xr2[2*k+1] = (v2f){v.z, v.w};
        }
        float4 t1 = *reinterpret_cast<const float4*>(xe + 16 + 4 * w);
        xrl2[0] = (v2f){t1.x, t1.y}; xrl2[1] = (v2f){t1.z, t1.w};
    }

    const v2f* Cv = reinterpret_cast<const v2f*>(C);   // table t: +t*128, row l: +l*8

    // ---- G over own 4 l's x 16 r's (8 pairs) ----
    v2f Scol[8];
    #pragma unroll
    for (int k = 0; k < 8; ++k) Scol[k] = (v2f){0.0f, 0.0f};
    float er[4];
    float pd = 0.0f;
    const float NSCL = -2.0f * LOG2E;

    #pragma unroll
    for (int i = 0; i < 4; ++i) {
        const int l = 4 * w + i;                       // wave-uniform
        const float xls = xl2[i >> 1][i & 1];
        const v2f xlv = (v2f){xls, xls};
        v2f rs = (v2f){0.0f, 0.0f};
        #pragma unroll
        for (int k = 0; k < 8; ++k) {
            v2f c1 = Cv[0 * 128 + l * 8 + k];
            v2f c2 = Cv[1 * 128 + l * 8 + k];
            v2f c3 = Cv[2 * 128 + l * 8 + k];
            v2f c4 = Cv[3 * 128 + l * 8 + k];
            v2f u = xlv * c1; u = u + c3;              // mul+add: 1 sgpr-pair each
            v2f q = xlv * c2; q = q + c4;
            v2f g = fma2(xr2[k], u, q);                // all-VGPR fma
            g = __builtin_elementwise_min(g, (v2f){88.0f, 88.0f});  // overflow guard
            v2f E; E.x = EXP2F(g.x); E.y = EXP2F(g.y);
            v2f D = E + 1.0f;
            // batched reciprocal: 1 rcp for both lanes of the pair
            float P = D.x * D.y;
            float t = RCPF(P);
            v2f rc; rc.x = D.y * t; rc.y = D.x * t;
            Scol[k] = Scol[k] + rc;
            rs = rs + rc;
        }
        float srow = rs.x + rs.y;
        er[i] = EXP2F(srow * NSCL);
        pd += er[i];
    }

    // ---- exchange 1: Scol partials + rl-denominator partial ----
    float* slot = ldsS + tid * 18;
    #pragma unroll
    for (int k = 0; k < 8; ++k) *reinterpret_cast<v2f*>(slot + 2 * k) = Scol[k];
    ldsP[tid] = pd;
    __syncthreads();

    // full Scol (for lr denominator) from 3 partners
    float denr = pd;
    #pragma unroll
    for (int p = 1; p < 4; ++p) {
        const int q = ((w + p) & 3) * 64 + lane;
        const float* ps = ldsS + q * 18;
        #pragma unroll
        for (int k = 0; k < 8; ++k)
            Scol[k] = Scol[k] + *reinterpret_cast<const v2f*>(ps + 2 * k);
        denr += ldsP[q];
    }
    float s = 0.0f;
    #pragma unroll
    for (int k = 0; k < 8; ++k) {
        v2f arg = Scol[k] * NSCL;
        s += EXP2F(arg.x) + EXP2F(arg.y);
    }
    const float invlr = RCPF(s);
    const float invrl = RCPF(denr);

    // own quarter of full Scol via LDS (static regs; no runtime reg-index)
    v2f q0 = (v2f){0.0f, 0.0f}, q1 = (v2f){0.0f, 0.0f};
    #pragma unroll
    for (int wp = 0; wp < 4; ++wp) {
        const float* ps = ldsS + (wp * 64 + lane) * 18 + 4 * w;
        q0 = q0 + *reinterpret_cast<const v2f*>(ps);
        q1 = q1 + *reinterpret_cast<const v2f*>(ps + 2);
    }
    v2f elrq0; elrq0.x = EXP2F(q0.x * NSCL); elrq0.y = EXP2F(q0.y * NSCL);
    v2f elrq1; elrq1.x = EXP2F(q1.x * NSCL); elrq1.y = EXP2F(q1.y * NSCL);

    __syncthreads();    // all ldsS reads done before o-partial rewrite

    // ---- dense: own 8 rows, partial over all 16 outputs ----
    v2f xa0 = xl2[0] * (elrq0 * invlr);    // x[4w..]*a_lr[4w..]
    v2f xa1 = xl2[1] * (elrq1 * invlr);
    v2f ar0; ar0.x = er[0] * invrl; ar0.y = er[1] * invrl;
    v2f ar1; ar1.x = er[2] * invrl; ar1.y = er[3] * invrl;
    v2f xb0 = xrl2[0] * ar0;               // x[16+4w..]*a_rl[4w..]
    v2f xb1 = xrl2[1] * ar1;

    const v2f* dW2  = reinterpret_cast<const v2f*>(dW);
    const v2f* db2v = reinterpret_cast<const v2f*>(db);
    v2f o2[8];
    if (w == 0) {
        #pragma unroll
        for (int m = 0; m < 8; ++m) o2[m] = db2v[m];   // db added exactly once
    } else {
        #pragma unroll
        for (int m = 0; m < 8; ++m) o2[m] = (v2f){0.0f, 0.0f};
    }
    #pragma unroll
    for (int i = 0; i < 4; ++i) {          // lr rows j = 4w+i
        const float xj = (i < 2 ? xa0 : xa1)[i & 1];
        const v2f xj2 = (v2f){xj, xj};
        const v2f* row = dW2 + (4 * w + i) * 8;
        #pragma unroll
        for (int m = 0; m < 8; ++m) o2[m] = fma2(xj2, row[m], o2[m]);
    }
    #pragma unroll
    for (int i = 0; i < 4; ++i) {          // rl rows j = 16+4w+i
        const float xj = (i < 2 ? xb0 : xb1)[i & 1];
        const v2f xj2 = (v2f){xj, xj};
        const v2f* row = dW2 + (16 + 4 * w + i) * 8;
        #pragma unroll
        for (int m = 0; m < 8; ++m) o2[m] = fma2(xj2, row[m], o2[m]);
    }

    // ---- exchange 2: sum 4 partials, each wave stores its out-quarter ----
    #pragma unroll
    for (int m = 0; m < 8; ++m) *reinterpret_cast<v2f*>(slot + 2 * m) = o2[m];
    __syncthreads();

    v2f f0 = (v2f){0.0f, 0.0f}, f1 = (v2f){0.0f, 0.0f};
    #pragma unroll
    for (int wp = 0; wp < 4; ++wp) {
        const float* ps = ldsS + (wp * 64 + lane) * 18 + 4 * w;
        f0 = f0 + *reinterpret_cast<const v2f*>(ps);
        f1 = f1 + *reinterpret_cast<const v2f*>(ps + 2);
    }
    const v2f z = (v2f){0.0f, 0.0f};
    f0 = __builtin_elementwise_max(f0, z);
    f1 = __builtin_elementwise_max(f1, z);
    float4 v; v.x = f0.x; v.y = f0.y; v.z = f1.x; v.w = f1.y;
    *reinterpret_cast<float4*>(out + e * 16 + 4 * w) = v;
}

extern "C" void kernel_launch(void* const* d_in, const int* in_sizes, int n_in,
                              void* d_out, int out_size, void* d_ws, size_t ws_size,
                              hipStream_t stream) {
    const float* x     = (const float*)d_in[0];
    const float* emb_W = (const float*)d_in[1];
    const float* emb_b = (const float*)d_in[2];
    const float* M     = (const float*)d_in[3];
    const float* dW    = (const float*)d_in[4];
    const float* db    = (const float*)d_in[5];
    float* out = (float*)d_out;
    float* C   = (float*)d_ws;          // 4 * 256 floats = 4 KB

    hipLaunchKernelGGL(coattn_setup, dim3(1), dim3(256), 0, stream,
                       emb_W, emb_b, M, C);

    const int B = in_sizes[0] / 32;     // 262144
    dim3 block(256);
    dim3 grid(B / 64);                  // 4 waves per 64 elements
    hipLaunchKernelGGL(coattn_kernel, grid, block, 0, stream,
                       x, C, dW, db, out);
}